// Round 11
// baseline (2378.446 us; speedup 1.0000x reference)
//
#include <hip/hip_runtime.h>
#include <hip/hip_bf16.h>
#include <cstdint>

#define B_ 256
#define T_ 512
#define F_ 128
#define H_ 128
#define G3_ 384
#define R_ 8
#define K_ 64

typedef __attribute__((ext_vector_type(8))) short short8_t;
typedef __attribute__((ext_vector_type(4))) float f32x4;
typedef __attribute__((ext_vector_type(2))) float f32x2;

__device__ __forceinline__ float sigm(float x) { return 1.f / (1.f + __expf(-x)); }
__device__ __forceinline__ float tanh_f(float x) { return 1.f - 2.f / (1.f + __expf(2.f * x)); }
// RNE float->bf16 (finite inputs)
__device__ __forceinline__ unsigned short f2bf(float f) {
    uint32_t u = __builtin_bit_cast(uint32_t, f);
    return (unsigned short)((u + 0x7FFFu + ((u >> 16) & 1u)) >> 16);
}
__device__ __forceinline__ short8_t pack8(float4 a, float4 b) {
    short8_t v;
    v[0] = (short)f2bf(a.x); v[1] = (short)f2bf(a.y);
    v[2] = (short)f2bf(a.z); v[3] = (short)f2bf(a.w);
    v[4] = (short)f2bf(b.x); v[5] = (short)f2bf(b.y);
    v[6] = (short)f2bf(b.z); v[7] = (short)f2bf(b.w);
    return v;
}

// Quad-local butterfly adds on the VALU pipe (DPP quad_perm).
__device__ __forceinline__ float dpp_red2(float x) {
    int a = __builtin_amdgcn_mov_dpp(__builtin_bit_cast(int, x), 0xB1, 0xF, 0xF, true);
    x += __builtin_bit_cast(float, a);
    int b = __builtin_amdgcn_mov_dpp(__builtin_bit_cast(int, x), 0x4E, 0xF, 0xF, true);
    x += __builtin_bit_cast(float, b);
    return x;
}

// MFMA GEMM: C[m][n] = sum_k A[m][k]*W[n][k] + bias[n], row-major C.
// M = B*T, N = 384. Block = 128 M x 384 N, 8 waves. W fragments (bf16)
// persist in VGPRs. A staged fp32->bf16 in XOR-swizzled LDS. fp32 accum.
__global__ __launch_bounds__(512, 2) void gemm_gi_mfma(const float* __restrict__ A,
                                                       const float* __restrict__ W,
                                                       const float* __restrict__ bias,
                                                       float* __restrict__ C)
{
    __shared__ alignas(16) unsigned short A_lds[128 * 128];  // bf16, swizzled

    const int tid = threadIdx.x;
    const int wv = tid >> 6, lane = tid & 63;
    const int lc = lane & 15, lg = lane >> 4;
    const size_t m0 = (size_t)blockIdx.x * 128;

    short8_t bf[3][4];
    float bi[3];
    #pragma unroll
    for (int u = 0; u < 3; ++u) {
        const int n = 48 * wv + 16 * u + lc;
        bi[u] = bias[n];
        #pragma unroll
        for (int ks = 0; ks < 4; ++ks) {
            const float4* wp = (const float4*)(W + (size_t)n * 128 + ks * 32 + lg * 8);
            bf[u][ks] = pack8(wp[0], wp[1]);
        }
    }

    {
        const int m = tid >> 2, kq = tid & 3;
        const float4* ap = (const float4*)(A + (m0 + m) * 128 + kq * 32);
        float4 v0 = ap[0], v1 = ap[1], v2 = ap[2], v3 = ap[3];
        float4 v4 = ap[4], v5 = ap[5], v6 = ap[6], v7 = ap[7];
        char* base = (char*)A_lds;
        const int bb = m * 256 + kq * 64, sw = (m & 7) << 4;
        *(short8_t*)(base + ((bb +  0) ^ sw)) = pack8(v0, v1);
        *(short8_t*)(base + ((bb + 16) ^ sw)) = pack8(v2, v3);
        *(short8_t*)(base + ((bb + 32) ^ sw)) = pack8(v4, v5);
        *(short8_t*)(base + ((bb + 48) ^ sw)) = pack8(v6, v7);
    }
    __syncthreads();

    const char* Ab = (const char*)A_lds;
    #pragma unroll 2
    for (int mt = 0; mt < 8; ++mt) {
        short8_t af0 = *(const short8_t*)(Ab + (((mt * 16 + lc) * 256 +  0 + lg * 16) ^ ((lc & 7) << 4)));
        short8_t af1 = *(const short8_t*)(Ab + (((mt * 16 + lc) * 256 + 64 + lg * 16) ^ ((lc & 7) << 4)));
        short8_t af2 = *(const short8_t*)(Ab + (((mt * 16 + lc) * 256 + 128 + lg * 16) ^ ((lc & 7) << 4)));
        short8_t af3 = *(const short8_t*)(Ab + (((mt * 16 + lc) * 256 + 192 + lg * 16) ^ ((lc & 7) << 4)));
        f32x4 a0 = {0.f, 0.f, 0.f, 0.f}, a1 = a0, a2 = a0;
        a0 = __builtin_amdgcn_mfma_f32_16x16x32_bf16(af0, bf[0][0], a0, 0, 0, 0);
        a1 = __builtin_amdgcn_mfma_f32_16x16x32_bf16(af0, bf[1][0], a1, 0, 0, 0);
        a2 = __builtin_amdgcn_mfma_f32_16x16x32_bf16(af0, bf[2][0], a2, 0, 0, 0);
        a0 = __builtin_amdgcn_mfma_f32_16x16x32_bf16(af1, bf[0][1], a0, 0, 0, 0);
        a1 = __builtin_amdgcn_mfma_f32_16x16x32_bf16(af1, bf[1][1], a1, 0, 0, 0);
        a2 = __builtin_amdgcn_mfma_f32_16x16x32_bf16(af1, bf[2][1], a2, 0, 0, 0);
        a0 = __builtin_amdgcn_mfma_f32_16x16x32_bf16(af2, bf[0][2], a0, 0, 0, 0);
        a1 = __builtin_amdgcn_mfma_f32_16x16x32_bf16(af2, bf[1][2], a1, 0, 0, 0);
        a2 = __builtin_amdgcn_mfma_f32_16x16x32_bf16(af2, bf[2][2], a2, 0, 0, 0);
        a0 = __builtin_amdgcn_mfma_f32_16x16x32_bf16(af3, bf[0][3], a0, 0, 0, 0);
        a1 = __builtin_amdgcn_mfma_f32_16x16x32_bf16(af3, bf[1][3], a1, 0, 0, 0);
        a2 = __builtin_amdgcn_mfma_f32_16x16x32_bf16(af3, bf[2][3], a2, 0, 0, 0);
        #pragma unroll
        for (int r = 0; r < 4; ++r) {
            float* cp = C + (m0 + mt * 16 + 4 * lg + r) * G3_ + 48 * wv + lc;
            cp[0]  = a0[r] + bi[0];
            cp[16] = a1[r] + bi[1];
            cp[32] = a2[r] + bi[2];
        }
    }
}

// TWO batch elements per 1024-thread block (each 512-thread half = one
// batch, identical r9 layout inside). 16 waves -> 4 waves/SIMD: same
// per-wave issue cost, twice the SIMD occupancy -> ~1020 cyc/batch-step
// instead of 1644. Grid = 128 blocks (all 256 batches still concurrent).
// Within a half: j = 16*(wave-in-half) + (lane>>2); k-chunk s = lane&3.
// Matvec f32x2 (v_pk_fma_f32); reduce via DPP quad-perm. h double-buffered
// per half. gi prefetched FOUR steps ahead. ONE raw s_barrier per step,
// lgkm-only drain.
__global__ __launch_bounds__(1024, 1) void gru_seq(const float* __restrict__ gi,
                                                   const float* __restrict__ Whh,
                                                   const float* __restrict__ bhh,
                                                   float* __restrict__ hout)
{
    __shared__ alignas(16) float hbuf[2][2][4][36];   // [half][p][chunk][...]

    const int tid = threadIdx.x;
    const int half = tid >> 9;
    const int tl = tid & 511;
    const int b = blockIdx.x * 2 + half;
    const int w = tl >> 6;                 // wave-in-half 0..7
    const int lane = tid & 63;
    const int j = 16 * w + (lane >> 2);
    const int s = lane & 3;
    const bool fin = (s == 0);

    // per-thread weights as fp32 PAIRS: rows j, 128+j, 256+j; cols [32s,32s+32)
    f32x2 wr2[16], wz2[16], wn2[16];
    {
        const float4* p0 = (const float4*)(Whh + (size_t)j * 128 + s * 32);
        const float4* p1 = (const float4*)(Whh + (size_t)(128 + j) * 128 + s * 32);
        const float4* p2 = (const float4*)(Whh + (size_t)(256 + j) * 128 + s * 32);
        #pragma unroll
        for (int q = 0; q < 8; ++q) {
            float4 v0 = p0[q], v1 = p1[q], v2 = p2[q];
            wr2[2*q]   = f32x2{v0.x, v0.y};
            wr2[2*q+1] = f32x2{v0.z, v0.w};
            wz2[2*q]   = f32x2{v1.x, v1.y};
            wz2[2*q+1] = f32x2{v1.z, v1.w};
            wn2[2*q]   = f32x2{v2.x, v2.y};
            wn2[2*q+1] = f32x2{v2.z, v2.w};
        }
    }
    const float br = bhh[j], bz = bhh[128 + j], bn = bhh[256 + j];

    if (tl < H_) hbuf[half][0][tl >> 5][tl & 31] = 0.f;
    __syncthreads();

    const float* gip = gi + (size_t)b * T_ * G3_ + j;
    float* hop = hout + (size_t)b * T_ * H_ + j;

    // 4-deep gi prefetch (finalize lanes only), named sets for static indexing
    float g0[3], g1[3], g2[3], g3[3];
    if (fin) {
        #pragma unroll
        for (int u = 0; u < 3; ++u) {
            g0[u] = gip[0 * G3_ + 128 * u];
            g1[u] = gip[1 * G3_ + 128 * u];
            g2[u] = gip[2 * G3_ + 128 * u];
            g3[u] = gip[3 * G3_ + 128 * u];
        }
    }
    float hprev = 0.f;

    auto step = [&](int t, float (&gc)[3]) {
        const int p = t & 1;
        const float4* hv = (const float4*)(&hbuf[half][p][s][0]);
        f32x2 pr2 = {0.f, 0.f}, pz2 = pr2, pn2 = pr2;
        #pragma unroll
        for (int q = 0; q < 8; ++q) {
            float4 h4 = hv[q];
            f32x2 ha = {h4.x, h4.y};
            f32x2 hb = {h4.z, h4.w};
            pr2 += wr2[2*q] * ha;  pr2 += wr2[2*q+1] * hb;
            pz2 += wz2[2*q] * ha;  pz2 += wz2[2*q+1] * hb;
            pn2 += wn2[2*q] * ha;  pn2 += wn2[2*q+1] * hb;
        }
        float pr = dpp_red2(pr2[0] + pr2[1]);
        float pz = dpp_red2(pz2[0] + pz2[1]);
        float pn = dpp_red2(pn2[0] + pn2[1]);

        if (fin) {
            float r  = sigm(gc[0] + pr + br);
            float z  = sigm(gc[1] + pz + bz);
            float nn = tanh_f(gc[2] + r * (pn + bn));
            float h  = (1.f - z) * nn + z * hprev;
            hprev = h;
            hbuf[half][p ^ 1][j >> 5][j & 31] = h;
            hop[(size_t)t * H_] = h;                     // fire-and-forget
            int tn = (t + 4 < T_) ? t + 4 : T_ - 1;
            const float* gp = gip + (size_t)tn * G3_;
            gc[0] = gp[0]; gc[1] = gp[128]; gc[2] = gp[256];
        }
        // LDS-only drain + raw barrier (global ops stay in flight)
        asm volatile("s_waitcnt lgkmcnt(0)" ::: "memory");
        __builtin_amdgcn_s_barrier();
    };

    for (int t = 0; t < T_; t += 4) {
        step(t + 0, g0);
        step(t + 1, g1);
        step(t + 2, g2);
        step(t + 3, g3);
    }
}

// One wave per sample: a = h2·W1[reg] + b1[reg]; SiLU; corr = a·W2[reg] + b2[reg]
__global__ __launch_bounds__(256) void head_k(const float* __restrict__ h2,
                                              const float* __restrict__ x,
                                              const int* __restrict__ regime,
                                              const float* __restrict__ W1,
                                              const float* __restrict__ b1,
                                              const float* __restrict__ W2,
                                              const float* __restrict__ b2,
                                              const float* __restrict__ lag_scale,
                                              const float* __restrict__ lag_bias,
                                              float* __restrict__ out)
{
    __shared__ alignas(16) float hrow[4][128];
    const int tid = threadIdx.x;
    const int wv = tid >> 6, lane = tid & 63;
    const size_t s = (size_t)blockIdx.x * 4 + wv;
    const int reg = regime[s];

    if (lane < 32)
        ((float4*)hrow[wv])[lane] = ((const float4*)(h2 + s * H_))[lane];
    __syncthreads();

    float acc = b1[reg * K_ + lane];
    const float* Wp = W1 + (size_t)reg * H_ * K_ + lane;
    const float4* h4p = (const float4*)hrow[wv];
    #pragma unroll
    for (int q = 0; q < 32; ++q) {
        float4 h4 = h4p[q];
        acc += h4.x * Wp[(4 * q + 0) * K_];
        acc += h4.y * Wp[(4 * q + 1) * K_];
        acc += h4.z * Wp[(4 * q + 2) * K_];
        acc += h4.w * Wp[(4 * q + 3) * K_];
    }
    float silu = acc * sigm(acc);
    float v = silu * W2[reg * K_ + lane];
    #pragma unroll
    for (int m = 1; m < 64; m <<= 1) v += __shfl_xor(v, m);
    if (lane == 0) {
        float lag = lag_scale[0] * x[s * F_] + lag_bias[0];
        out[s] = lag + v + b2[reg];
    }
}

extern "C" void kernel_launch(void* const* d_in, const int* in_sizes, int n_in,
                              void* d_out, int out_size, void* d_ws, size_t ws_size,
                              hipStream_t stream) {
    const float* x         = (const float*)d_in[0];
    const int*   regime    = (const int*)d_in[1];
    const float* lag_scale = (const float*)d_in[2];
    const float* lag_bias  = (const float*)d_in[3];
    const float* Wih0      = (const float*)d_in[4];
    const float* Whh0      = (const float*)d_in[5];
    const float* bih0      = (const float*)d_in[6];
    const float* bhh0      = (const float*)d_in[7];
    const float* Wih1      = (const float*)d_in[8];
    const float* Whh1      = (const float*)d_in[9];
    const float* bih1      = (const float*)d_in[10];
    const float* bhh1      = (const float*)d_in[11];
    const float* W1        = (const float*)d_in[12];
    const float* b1        = (const float*)d_in[13];
    const float* W2        = (const float*)d_in[14];
    const float* b2        = (const float*)d_in[15];
    float* out = (float*)d_out;

    const size_t NT = (size_t)B_ * T_;               // 131072
    const size_t need = NT * G3_ * 4 + NT * H_ * 4;  // 256 MiB
    if (ws_size < need) {
        hipMemsetAsync(d_out, 0x7F, (size_t)out_size * 4, stream);
        return;
    }
    float* gi = (float*)d_ws;
    float* hb = gi + NT * G3_;                       // h1, then reused as h2

    const int gblocks = (int)(NT / 128);             // 1024
    gemm_gi_mfma<<<gblocks, 512, 0, stream>>>(x, Wih0, bih0, gi);
    gru_seq<<<B_ / 2, 1024, 0, stream>>>(gi, Whh0, bhh0, hb);
    gemm_gi_mfma<<<gblocks, 512, 0, stream>>>(hb, Wih1, bih1, gi);
    gru_seq<<<B_ / 2, 1024, 0, stream>>>(gi, Whh1, bhh1, hb);
    head_k<<<(int)(NT / 4), 256, 0, stream>>>(hb, x, regime, W1, b1, W2, b2,
                                              lag_scale, lag_bias, out);
}

// Round 12
// 1135.243 us; speedup vs baseline: 2.0951x; 2.0951x over previous
//
#include <hip/hip_runtime.h>
#include <hip/hip_bf16.h>
#include <cstdint>

#define B_ 256
#define T_ 512
#define F_ 128
#define H_ 128
#define G3_ 384
#define R_ 8
#define K_ 64
#define NT_ 131072

typedef __attribute__((ext_vector_type(8))) short short8_t;
typedef __attribute__((ext_vector_type(4))) float f32x4;
typedef __attribute__((ext_vector_type(2))) float f32x2;

__device__ __forceinline__ float sigm(float x) { return 1.f / (1.f + __expf(-x)); }
__device__ __forceinline__ float tanh_f(float x) { return 1.f - 2.f / (1.f + __expf(2.f * x)); }
__device__ __forceinline__ unsigned short f2bf(float f) {
    uint32_t u = __builtin_bit_cast(uint32_t, f);
    return (unsigned short)((u + 0x7FFFu + ((u >> 16) & 1u)) >> 16);
}
__device__ __forceinline__ short8_t pack8(float4 a, float4 b) {
    short8_t v;
    v[0] = (short)f2bf(a.x); v[1] = (short)f2bf(a.y);
    v[2] = (short)f2bf(a.z); v[3] = (short)f2bf(a.w);
    v[4] = (short)f2bf(b.x); v[5] = (short)f2bf(b.y);
    v[6] = (short)f2bf(b.z); v[7] = (short)f2bf(b.w);
    return v;
}

// Quad-local butterfly adds on the VALU pipe (DPP quad_perm).
__device__ __forceinline__ float dpp_red2(float x) {
    int a = __builtin_amdgcn_mov_dpp(__builtin_bit_cast(int, x), 0xB1, 0xF, 0xF, true);
    x += __builtin_bit_cast(float, a);
    int b = __builtin_amdgcn_mov_dpp(__builtin_bit_cast(int, x), 0x4E, 0xF, 0xF, true);
    x += __builtin_bit_cast(float, b);
    return x;
}

// MFMA GEMM: C[m][n] = sum_k A[m][k]*W[n][k] + bias[n], row-major C.
__global__ __launch_bounds__(512, 2) void gemm_gi_mfma(const float* __restrict__ A,
                                                       const float* __restrict__ W,
                                                       const float* __restrict__ bias,
                                                       float* __restrict__ C)
{
    __shared__ alignas(16) unsigned short A_lds[128 * 128];  // bf16, swizzled

    const int tid = threadIdx.x;
    const int wv = tid >> 6, lane = tid & 63;
    const int lc = lane & 15, lg = lane >> 4;
    const size_t m0 = (size_t)blockIdx.x * 128;

    short8_t bf[3][4];
    float bi[3];
    #pragma unroll
    for (int u = 0; u < 3; ++u) {
        const int n = 48 * wv + 16 * u + lc;
        bi[u] = bias[n];
        #pragma unroll
        for (int ks = 0; ks < 4; ++ks) {
            const float4* wp = (const float4*)(W + (size_t)n * 128 + ks * 32 + lg * 8);
            bf[u][ks] = pack8(wp[0], wp[1]);
        }
    }

    {
        const int m = tid >> 2, kq = tid & 3;
        const float4* ap = (const float4*)(A + (m0 + m) * 128 + kq * 32);
        float4 v0 = ap[0], v1 = ap[1], v2 = ap[2], v3 = ap[3];
        float4 v4 = ap[4], v5 = ap[5], v6 = ap[6], v7 = ap[7];
        char* base = (char*)A_lds;
        const int bb = m * 256 + kq * 64, sw = (m & 7) << 4;
        *(short8_t*)(base + ((bb +  0) ^ sw)) = pack8(v0, v1);
        *(short8_t*)(base + ((bb + 16) ^ sw)) = pack8(v2, v3);
        *(short8_t*)(base + ((bb + 32) ^ sw)) = pack8(v4, v5);
        *(short8_t*)(base + ((bb + 48) ^ sw)) = pack8(v6, v7);
    }
    __syncthreads();

    const char* Ab = (const char*)A_lds;
    #pragma unroll 2
    for (int mt = 0; mt < 8; ++mt) {
        short8_t af0 = *(const short8_t*)(Ab + (((mt * 16 + lc) * 256 +  0 + lg * 16) ^ ((lc & 7) << 4)));
        short8_t af1 = *(const short8_t*)(Ab + (((mt * 16 + lc) * 256 + 64 + lg * 16) ^ ((lc & 7) << 4)));
        short8_t af2 = *(const short8_t*)(Ab + (((mt * 16 + lc) * 256 + 128 + lg * 16) ^ ((lc & 7) << 4)));
        short8_t af3 = *(const short8_t*)(Ab + (((mt * 16 + lc) * 256 + 192 + lg * 16) ^ ((lc & 7) << 4)));
        f32x4 a0 = {0.f, 0.f, 0.f, 0.f}, a1 = a0, a2 = a0;
        a0 = __builtin_amdgcn_mfma_f32_16x16x32_bf16(af0, bf[0][0], a0, 0, 0, 0);
        a1 = __builtin_amdgcn_mfma_f32_16x16x32_bf16(af0, bf[1][0], a1, 0, 0, 0);
        a2 = __builtin_amdgcn_mfma_f32_16x16x32_bf16(af0, bf[2][0], a2, 0, 0, 0);
        a0 = __builtin_amdgcn_mfma_f32_16x16x32_bf16(af1, bf[0][1], a0, 0, 0, 0);
        a1 = __builtin_amdgcn_mfma_f32_16x16x32_bf16(af1, bf[1][1], a1, 0, 0, 0);
        a2 = __builtin_amdgcn_mfma_f32_16x16x32_bf16(af1, bf[2][1], a2, 0, 0, 0);
        a0 = __builtin_amdgcn_mfma_f32_16x16x32_bf16(af2, bf[0][2], a0, 0, 0, 0);
        a1 = __builtin_amdgcn_mfma_f32_16x16x32_bf16(af2, bf[1][2], a1, 0, 0, 0);
        a2 = __builtin_amdgcn_mfma_f32_16x16x32_bf16(af2, bf[2][2], a2, 0, 0, 0);
        a0 = __builtin_amdgcn_mfma_f32_16x16x32_bf16(af3, bf[0][3], a0, 0, 0, 0);
        a1 = __builtin_amdgcn_mfma_f32_16x16x32_bf16(af3, bf[1][3], a1, 0, 0, 0);
        a2 = __builtin_amdgcn_mfma_f32_16x16x32_bf16(af3, bf[2][3], a2, 0, 0, 0);
        #pragma unroll
        for (int r = 0; r < 4; ++r) {
            float* cp = C + (m0 + mt * 16 + 4 * lg + r) * G3_ + 48 * wv + lc;
            cp[0]  = a0[r] + bi[0];
            cp[16] = a1[r] + bi[1];
            cp[32] = a2[r] + bi[2];
        }
    }
}

// r9-exact recurrence (948 us total config): one 512-thread block per batch,
// f32x2 matvec (v_pk_fma_f32), DPP quad-perm reduce, [4][36] LDS h dbuf,
// 4-deep gi prefetch, ONE raw s_barrier per step with lgkm-only drain.
__global__ __launch_bounds__(512, 2) void gru_seq(const float* __restrict__ gi,
                                                  const float* __restrict__ Whh,
                                                  const float* __restrict__ bhh,
                                                  float* __restrict__ hout)
{
    __shared__ alignas(16) float hbuf[2][4][36];

    const int tid = threadIdx.x;
    const int b = blockIdx.x;
    const int w = tid >> 6, lane = tid & 63;
    const int j = 16 * w + (lane >> 2);
    const int s = lane & 3;
    const bool fin = (s == 0);

    f32x2 wr2[16], wz2[16], wn2[16];
    {
        const float4* p0 = (const float4*)(Whh + (size_t)j * 128 + s * 32);
        const float4* p1 = (const float4*)(Whh + (size_t)(128 + j) * 128 + s * 32);
        const float4* p2 = (const float4*)(Whh + (size_t)(256 + j) * 128 + s * 32);
        #pragma unroll
        for (int q = 0; q < 8; ++q) {
            float4 v0 = p0[q], v1 = p1[q], v2 = p2[q];
            wr2[2*q]   = f32x2{v0.x, v0.y};
            wr2[2*q+1] = f32x2{v0.z, v0.w};
            wz2[2*q]   = f32x2{v1.x, v1.y};
            wz2[2*q+1] = f32x2{v1.z, v1.w};
            wn2[2*q]   = f32x2{v2.x, v2.y};
            wn2[2*q+1] = f32x2{v2.z, v2.w};
        }
    }
    const float br = bhh[j], bz = bhh[128 + j], bn = bhh[256 + j];

    if (tid < H_) hbuf[0][tid >> 5][tid & 31] = 0.f;
    __syncthreads();

    const float* gip = gi + (size_t)b * T_ * G3_ + j;
    float* hop = hout + (size_t)b * T_ * H_ + j;

    float g0[3], g1[3], g2[3], g3[3];
    if (fin) {
        #pragma unroll
        for (int u = 0; u < 3; ++u) {
            g0[u] = gip[0 * G3_ + 128 * u];
            g1[u] = gip[1 * G3_ + 128 * u];
            g2[u] = gip[2 * G3_ + 128 * u];
            g3[u] = gip[3 * G3_ + 128 * u];
        }
    }
    float hprev = 0.f;

    auto step = [&](int t, float (&gc)[3]) {
        const int p = t & 1;
        const float4* hv = (const float4*)(&hbuf[p][s][0]);
        f32x2 pr2 = {0.f, 0.f}, pz2 = pr2, pn2 = pr2;
        #pragma unroll
        for (int q = 0; q < 8; ++q) {
            float4 h4 = hv[q];
            f32x2 ha = {h4.x, h4.y};
            f32x2 hb = {h4.z, h4.w};
            pr2 += wr2[2*q] * ha;  pr2 += wr2[2*q+1] * hb;
            pz2 += wz2[2*q] * ha;  pz2 += wz2[2*q+1] * hb;
            pn2 += wn2[2*q] * ha;  pn2 += wn2[2*q+1] * hb;
        }
        float pr = dpp_red2(pr2[0] + pr2[1]);
        float pz = dpp_red2(pz2[0] + pz2[1]);
        float pn = dpp_red2(pn2[0] + pn2[1]);

        if (fin) {
            float r  = sigm(gc[0] + pr + br);
            float z  = sigm(gc[1] + pz + bz);
            float nn = tanh_f(gc[2] + r * (pn + bn));
            float h  = (1.f - z) * nn + z * hprev;
            hprev = h;
            hbuf[p ^ 1][j >> 5][j & 31] = h;
            hop[(size_t)t * H_] = h;
            int tn = (t + 4 < T_) ? t + 4 : T_ - 1;
            const float* gp = gip + (size_t)tn * G3_;
            gc[0] = gp[0]; gc[1] = gp[128]; gc[2] = gp[256];
        }
        asm volatile("s_waitcnt lgkmcnt(0)" ::: "memory");
        __builtin_amdgcn_s_barrier();
    };

    for (int t = 0; t < T_; t += 4) {
        step(t + 0, g0);
        step(t + 1, g1);
        step(t + 2, g2);
        step(t + 3, g3);
    }
}

// Bucket samples by regime: wave-aggregated atomics (8 per wave max).
__global__ __launch_bounds__(256) void scatter_k(const int* __restrict__ regime,
                                                 int* __restrict__ cnt,
                                                 int* __restrict__ list)
{
    const int i = blockIdx.x * 256 + threadIdx.x;
    const int lane = threadIdx.x & 63;
    const int r = regime[i];
    #pragma unroll
    for (int rr = 0; rr < R_; ++rr) {
        unsigned long long m = __ballot(r == rr);
        if (m == 0ull) continue;
        int leader = __ffsll((unsigned long long)m) - 1;
        int base = 0;
        if (lane == leader) base = atomicAdd(&cnt[rr], __popcll(m));
        base = __shfl(base, leader);
        if (r == rr) {
            int off = __popcll(m & ((1ull << lane) - 1ull));
            list[rr * NT_ + base + off] = i;
        }
    }
}

// Regime-bucketed head: block = (regime, 64-sample segment). W1[reg] column
// held in registers per lane (lane k owns W1[:,k]); h2 row staged per wave
// in LDS and consumed via broadcast b64 reads. W1 L2 traffic: 4.3GB -> 64MB.
__global__ __launch_bounds__(512, 1) void head_bucket(const float* __restrict__ h2,
                                                      const float* __restrict__ x,
                                                      const float* __restrict__ W1,
                                                      const float* __restrict__ b1,
                                                      const float* __restrict__ W2,
                                                      const float* __restrict__ b2,
                                                      const float* __restrict__ lag_scale,
                                                      const float* __restrict__ lag_bias,
                                                      const int* __restrict__ cnt,
                                                      const int* __restrict__ list,
                                                      float* __restrict__ out)
{
    __shared__ alignas(16) float hstage[8][130];

    const int reg = blockIdx.x >> 11;          // 8 regimes x 2048 segments
    const int seg = blockIdx.x & 2047;
    const int n = cnt[reg];
    if (seg * 64 >= n) return;

    const int tid = threadIdx.x, w = tid >> 6, lane = tid & 63;

    // lane k holds W1[reg][h][k] for h = 0..127, as 64 fp32 pairs
    f32x2 w1c[64];
    const float* W1r = W1 + (size_t)reg * H_ * K_ + lane;
    #pragma unroll
    for (int q = 0; q < 64; ++q) {
        w1c[q][0] = W1r[(2 * q) * K_];
        w1c[q][1] = W1r[(2 * q + 1) * K_];
    }
    const float b1v = b1[reg * K_ + lane];
    const float w2v = W2[reg * K_ + lane];
    const float b2v = b2[reg];
    const float ls = lag_scale[0], lb = lag_bias[0];

    for (int it = 0; it < 8; ++it) {
        const int slot = seg * 64 + it * 8 + w;      // wave-uniform
        if (slot >= n) break;
        const int s = list[reg * NT_ + slot];

        float2 hp = *(const float2*)(h2 + (size_t)s * H_ + 2 * lane);
        hstage[w][2 * lane] = hp.x;
        hstage[w][2 * lane + 1] = hp.y;              // compiler inserts lgkm wait

        f32x2 acc2 = {b1v, 0.f};
        #pragma unroll
        for (int q = 0; q < 64; ++q) {
            f32x2 hb = *(const f32x2*)&hstage[w][2 * q];   // broadcast read
            acc2 += w1c[q] * hb;
        }
        float a = acc2[0] + acc2[1];
        float v = a * sigm(a) * w2v;
        #pragma unroll
        for (int m = 1; m < 64; m <<= 1) v += __shfl_xor(v, m);
        if (lane == 0)
            out[s] = ls * x[(size_t)s * F_] + lb + v + b2v;
    }
}

extern "C" void kernel_launch(void* const* d_in, const int* in_sizes, int n_in,
                              void* d_out, int out_size, void* d_ws, size_t ws_size,
                              hipStream_t stream) {
    const float* x         = (const float*)d_in[0];
    const int*   regime    = (const int*)d_in[1];
    const float* lag_scale = (const float*)d_in[2];
    const float* lag_bias  = (const float*)d_in[3];
    const float* Wih0      = (const float*)d_in[4];
    const float* Whh0      = (const float*)d_in[5];
    const float* bih0      = (const float*)d_in[6];
    const float* bhh0      = (const float*)d_in[7];
    const float* Wih1      = (const float*)d_in[8];
    const float* Whh1      = (const float*)d_in[9];
    const float* bih1      = (const float*)d_in[10];
    const float* bhh1      = (const float*)d_in[11];
    const float* W1        = (const float*)d_in[12];
    const float* b1        = (const float*)d_in[13];
    const float* W2        = (const float*)d_in[14];
    const float* b2        = (const float*)d_in[15];
    float* out = (float*)d_out;

    const size_t NT = (size_t)B_ * T_;               // 131072
    const size_t need = NT * G3_ * 4 + NT * H_ * 4;  // 256 MiB
    if (ws_size < need) {
        hipMemsetAsync(d_out, 0x7F, (size_t)out_size * 4, stream);
        return;
    }
    float* gi = (float*)d_ws;
    float* hb = gi + NT * G3_;                       // h1, then reused as h2

    // Bucket scratch reuses the gi region (dead after gru2 in stream order).
    int* cnt  = (int*)d_ws;                          // 8 counters (pad to 64)
    int* list = (int*)d_ws + 64;                     // 8 x 131072 indices

    const int gblocks = (int)(NT / 128);             // 1024
    gemm_gi_mfma<<<gblocks, 512, 0, stream>>>(x, Wih0, bih0, gi);
    gru_seq<<<B_, 512, 0, stream>>>(gi, Whh0, bhh0, hb);
    gemm_gi_mfma<<<gblocks, 512, 0, stream>>>(hb, Wih1, bih1, gi);
    gru_seq<<<B_, 512, 0, stream>>>(gi, Whh1, bhh1, hb);

    hipMemsetAsync(cnt, 0, 64 * sizeof(int), stream);
    scatter_k<<<(int)(NT / 256), 256, 0, stream>>>(regime, cnt, list);
    head_bucket<<<R_ * 2048, 512, 0, stream>>>(hb, x, W1, b1, W2, b2,
                                               lag_scale, lag_bias, cnt, list, out);
}

// Round 13
// 940.226 us; speedup vs baseline: 2.5297x; 1.2074x over previous
//
#include <hip/hip_runtime.h>
#include <hip/hip_bf16.h>
#include <cstdint>

#define B_ 256
#define T_ 512
#define F_ 128
#define H_ 128
#define G3_ 384
#define R_ 8
#define K_ 64

typedef __attribute__((ext_vector_type(8))) short short8_t;
typedef __attribute__((ext_vector_type(4))) float f32x4;
typedef __attribute__((ext_vector_type(2))) float f32x2;

__device__ __forceinline__ float sigm(float x) { return 1.f / (1.f + __expf(-x)); }
__device__ __forceinline__ float tanh_f(float x) { return 1.f - 2.f / (1.f + __expf(2.f * x)); }
__device__ __forceinline__ unsigned short f2bf(float f) {
    uint32_t u = __builtin_bit_cast(uint32_t, f);
    return (unsigned short)((u + 0x7FFFu + ((u >> 16) & 1u)) >> 16);
}
__device__ __forceinline__ short8_t pack8(float4 a, float4 b) {
    short8_t v;
    v[0] = (short)f2bf(a.x); v[1] = (short)f2bf(a.y);
    v[2] = (short)f2bf(a.z); v[3] = (short)f2bf(a.w);
    v[4] = (short)f2bf(b.x); v[5] = (short)f2bf(b.y);
    v[6] = (short)f2bf(b.z); v[7] = (short)f2bf(b.w);
    return v;
}

// Quad-local butterfly adds on the VALU pipe (DPP quad_perm).
__device__ __forceinline__ float dpp_red2(float x) {
    int a = __builtin_amdgcn_mov_dpp(__builtin_bit_cast(int, x), 0xB1, 0xF, 0xF, true);
    x += __builtin_bit_cast(float, a);
    int b = __builtin_amdgcn_mov_dpp(__builtin_bit_cast(int, x), 0x4E, 0xF, 0xF, true);
    x += __builtin_bit_cast(float, b);
    return x;
}

// MFMA GEMM: C[m][n] = sum_k A[m][k]*W[n][k] + bias[n], row-major C.
// NEW epilogue: D restaged through LDS per 16-row strip so global stores are
// fully-contiguous dwordx4 (each strip = 16x384 fp32 = 24KB linear region).
// Raw barriers with lgkm-only drain keep stores fire-and-forget.
__global__ __launch_bounds__(512, 2) void gemm_gi_mfma(const float* __restrict__ A,
                                                       const float* __restrict__ W,
                                                       const float* __restrict__ bias,
                                                       float* __restrict__ C)
{
    __shared__ alignas(16) unsigned short A_lds[128 * 128];  // bf16, swizzled, 32KB
    __shared__ alignas(16) float D_lds[16 * 384];            // restage strip, 24KB

    const int tid = threadIdx.x;
    const int wv = tid >> 6, lane = tid & 63;
    const int lc = lane & 15, lg = lane >> 4;
    const size_t m0 = (size_t)blockIdx.x * 128;

    short8_t bf[3][4];
    float bi[3];
    #pragma unroll
    for (int u = 0; u < 3; ++u) {
        const int n = 48 * wv + 16 * u + lc;
        bi[u] = bias[n];
        #pragma unroll
        for (int ks = 0; ks < 4; ++ks) {
            const float4* wp = (const float4*)(W + (size_t)n * 128 + ks * 32 + lg * 8);
            bf[u][ks] = pack8(wp[0], wp[1]);
        }
    }

    {
        const int m = tid >> 2, kq = tid & 3;
        const float4* ap = (const float4*)(A + (m0 + m) * 128 + kq * 32);
        float4 v0 = ap[0], v1 = ap[1], v2 = ap[2], v3 = ap[3];
        float4 v4 = ap[4], v5 = ap[5], v6 = ap[6], v7 = ap[7];
        char* base = (char*)A_lds;
        const int bb = m * 256 + kq * 64, sw = (m & 7) << 4;
        *(short8_t*)(base + ((bb +  0) ^ sw)) = pack8(v0, v1);
        *(short8_t*)(base + ((bb + 16) ^ sw)) = pack8(v2, v3);
        *(short8_t*)(base + ((bb + 32) ^ sw)) = pack8(v4, v5);
        *(short8_t*)(base + ((bb + 48) ^ sw)) = pack8(v6, v7);
    }
    __syncthreads();

    const char* Ab = (const char*)A_lds;
    for (int mt = 0; mt < 8; ++mt) {
        short8_t af0 = *(const short8_t*)(Ab + (((mt * 16 + lc) * 256 +  0 + lg * 16) ^ ((lc & 7) << 4)));
        short8_t af1 = *(const short8_t*)(Ab + (((mt * 16 + lc) * 256 + 64 + lg * 16) ^ ((lc & 7) << 4)));
        short8_t af2 = *(const short8_t*)(Ab + (((mt * 16 + lc) * 256 + 128 + lg * 16) ^ ((lc & 7) << 4)));
        short8_t af3 = *(const short8_t*)(Ab + (((mt * 16 + lc) * 256 + 192 + lg * 16) ^ ((lc & 7) << 4)));
        f32x4 a0 = {0.f, 0.f, 0.f, 0.f}, a1 = a0, a2 = a0;
        a0 = __builtin_amdgcn_mfma_f32_16x16x32_bf16(af0, bf[0][0], a0, 0, 0, 0);
        a1 = __builtin_amdgcn_mfma_f32_16x16x32_bf16(af0, bf[1][0], a1, 0, 0, 0);
        a2 = __builtin_amdgcn_mfma_f32_16x16x32_bf16(af0, bf[2][0], a2, 0, 0, 0);
        a0 = __builtin_amdgcn_mfma_f32_16x16x32_bf16(af1, bf[0][1], a0, 0, 0, 0);
        a1 = __builtin_amdgcn_mfma_f32_16x16x32_bf16(af1, bf[1][1], a1, 0, 0, 0);
        a2 = __builtin_amdgcn_mfma_f32_16x16x32_bf16(af1, bf[2][1], a2, 0, 0, 0);
        a0 = __builtin_amdgcn_mfma_f32_16x16x32_bf16(af2, bf[0][2], a0, 0, 0, 0);
        a1 = __builtin_amdgcn_mfma_f32_16x16x32_bf16(af2, bf[1][2], a1, 0, 0, 0);
        a2 = __builtin_amdgcn_mfma_f32_16x16x32_bf16(af2, bf[2][2], a2, 0, 0, 0);
        a0 = __builtin_amdgcn_mfma_f32_16x16x32_bf16(af3, bf[0][3], a0, 0, 0, 0);
        a1 = __builtin_amdgcn_mfma_f32_16x16x32_bf16(af3, bf[1][3], a1, 0, 0, 0);
        a2 = __builtin_amdgcn_mfma_f32_16x16x32_bf16(af3, bf[2][3], a2, 0, 0, 0);

        // ---- restage D strip: regs -> LDS (ensure prior reads done first)
        asm volatile("s_waitcnt lgkmcnt(0)" ::: "memory");
        __builtin_amdgcn_s_barrier();
        #pragma unroll
        for (int r = 0; r < 4; ++r) {
            float* dp = D_lds + (4 * lg + r) * 384 + 48 * wv + lc;
            dp[0]  = a0[r] + bi[0];
            dp[16] = a1[r] + bi[1];
            dp[32] = a2[r] + bi[2];
        }
        asm volatile("s_waitcnt lgkmcnt(0)" ::: "memory");
        __builtin_amdgcn_s_barrier();

        // ---- LDS -> global: strip is contiguous 16*384 floats at row m0+mt*16
        float* cbase = C + (m0 + mt * 16) * G3_;
        const float4* dl4 = (const float4*)D_lds;
        float4* cg4 = (float4*)cbase;
        #pragma unroll
        for (int i = 0; i < 3; ++i) {
            int f = tid + 512 * i;            // 1536 float4 total
            cg4[f] = dl4[f];                  // fire-and-forget store
        }
    }
}

// r9-exact recurrence: one 512-thread block per batch, f32x2 matvec
// (v_pk_fma_f32), DPP quad-perm reduce, [4][36] LDS h dbuf, 4-deep gi
// prefetch, ONE raw s_barrier per step with lgkm-only drain.
__global__ __launch_bounds__(512, 2) void gru_seq(const float* __restrict__ gi,
                                                  const float* __restrict__ Whh,
                                                  const float* __restrict__ bhh,
                                                  float* __restrict__ hout)
{
    __shared__ alignas(16) float hbuf[2][4][36];

    const int tid = threadIdx.x;
    const int b = blockIdx.x;
    const int w = tid >> 6, lane = tid & 63;
    const int j = 16 * w + (lane >> 2);
    const int s = lane & 3;
    const bool fin = (s == 0);

    f32x2 wr2[16], wz2[16], wn2[16];
    {
        const float4* p0 = (const float4*)(Whh + (size_t)j * 128 + s * 32);
        const float4* p1 = (const float4*)(Whh + (size_t)(128 + j) * 128 + s * 32);
        const float4* p2 = (const float4*)(Whh + (size_t)(256 + j) * 128 + s * 32);
        #pragma unroll
        for (int q = 0; q < 8; ++q) {
            float4 v0 = p0[q], v1 = p1[q], v2 = p2[q];
            wr2[2*q]   = f32x2{v0.x, v0.y};
            wr2[2*q+1] = f32x2{v0.z, v0.w};
            wz2[2*q]   = f32x2{v1.x, v1.y};
            wz2[2*q+1] = f32x2{v1.z, v1.w};
            wn2[2*q]   = f32x2{v2.x, v2.y};
            wn2[2*q+1] = f32x2{v2.z, v2.w};
        }
    }
    const float br = bhh[j], bz = bhh[128 + j], bn = bhh[256 + j];

    if (tid < H_) hbuf[0][tid >> 5][tid & 31] = 0.f;
    __syncthreads();

    const float* gip = gi + (size_t)b * T_ * G3_ + j;
    float* hop = hout + (size_t)b * T_ * H_ + j;

    float g0[3], g1[3], g2[3], g3[3];
    if (fin) {
        #pragma unroll
        for (int u = 0; u < 3; ++u) {
            g0[u] = gip[0 * G3_ + 128 * u];
            g1[u] = gip[1 * G3_ + 128 * u];
            g2[u] = gip[2 * G3_ + 128 * u];
            g3[u] = gip[3 * G3_ + 128 * u];
        }
    }
    float hprev = 0.f;

    auto step = [&](int t, float (&gc)[3]) {
        const int p = t & 1;
        const float4* hv = (const float4*)(&hbuf[p][s][0]);
        f32x2 pr2 = {0.f, 0.f}, pz2 = pr2, pn2 = pr2;
        #pragma unroll
        for (int q = 0; q < 8; ++q) {
            float4 h4 = hv[q];
            f32x2 ha = {h4.x, h4.y};
            f32x2 hb = {h4.z, h4.w};
            pr2 += wr2[2*q] * ha;  pr2 += wr2[2*q+1] * hb;
            pz2 += wz2[2*q] * ha;  pz2 += wz2[2*q+1] * hb;
            pn2 += wn2[2*q] * ha;  pn2 += wn2[2*q+1] * hb;
        }
        float pr = dpp_red2(pr2[0] + pr2[1]);
        float pz = dpp_red2(pz2[0] + pz2[1]);
        float pn = dpp_red2(pn2[0] + pn2[1]);

        if (fin) {
            float r  = sigm(gc[0] + pr + br);
            float z  = sigm(gc[1] + pz + bz);
            float nn = tanh_f(gc[2] + r * (pn + bn));
            float h  = (1.f - z) * nn + z * hprev;
            hprev = h;
            hbuf[p ^ 1][j >> 5][j & 31] = h;
            hop[(size_t)t * H_] = h;
            int tn = (t + 4 < T_) ? t + 4 : T_ - 1;
            const float* gp = gip + (size_t)tn * G3_;
            gc[0] = gp[0]; gc[1] = gp[128]; gc[2] = gp[256];
        }
        asm volatile("s_waitcnt lgkmcnt(0)" ::: "memory");
        __builtin_amdgcn_s_barrier();
    };

    for (int t = 0; t < T_; t += 4) {
        step(t + 0, g0);
        step(t + 1, g1);
        step(t + 2, g2);
        step(t + 3, g3);
    }
}

// One wave per sample: a = h2·W1[reg] + b1[reg]; SiLU; corr = a·W2[reg] + b2[reg]
__global__ __launch_bounds__(256) void head_k(const float* __restrict__ h2,
                                              const float* __restrict__ x,
                                              const int* __restrict__ regime,
                                              const float* __restrict__ W1,
                                              const float* __restrict__ b1,
                                              const float* __restrict__ W2,
                                              const float* __restrict__ b2,
                                              const float* __restrict__ lag_scale,
                                              const float* __restrict__ lag_bias,
                                              float* __restrict__ out)
{
    __shared__ alignas(16) float hrow[4][128];
    const int tid = threadIdx.x;
    const int wv = tid >> 6, lane = tid & 63;
    const size_t s = (size_t)blockIdx.x * 4 + wv;
    const int reg = regime[s];

    if (lane < 32)
        ((float4*)hrow[wv])[lane] = ((const float4*)(h2 + s * H_))[lane];
    __syncthreads();

    float acc = b1[reg * K_ + lane];
    const float* Wp = W1 + (size_t)reg * H_ * K_ + lane;
    const float4* h4p = (const float4*)hrow[wv];
    #pragma unroll
    for (int q = 0; q < 32; ++q) {
        float4 h4 = h4p[q];
        acc += h4.x * Wp[(4 * q + 0) * K_];
        acc += h4.y * Wp[(4 * q + 1) * K_];
        acc += h4.z * Wp[(4 * q + 2) * K_];
        acc += h4.w * Wp[(4 * q + 3) * K_];
    }
    float silu = acc * sigm(acc);
    float v = silu * W2[reg * K_ + lane];
    #pragma unroll
    for (int m = 1; m < 64; m <<= 1) v += __shfl_xor(v, m);
    if (lane == 0) {
        float lag = lag_scale[0] * x[s * F_] + lag_bias[0];
        out[s] = lag + v + b2[reg];
    }
}

extern "C" void kernel_launch(void* const* d_in, const int* in_sizes, int n_in,
                              void* d_out, int out_size, void* d_ws, size_t ws_size,
                              hipStream_t stream) {
    const float* x         = (const float*)d_in[0];
    const int*   regime    = (const int*)d_in[1];
    const float* lag_scale = (const float*)d_in[2];
    const float* lag_bias  = (const float*)d_in[3];
    const float* Wih0      = (const float*)d_in[4];
    const float* Whh0      = (const float*)d_in[5];
    const float* bih0      = (const float*)d_in[6];
    const float* bhh0      = (const float*)d_in[7];
    const float* Wih1      = (const float*)d_in[8];
    const float* Whh1      = (const float*)d_in[9];
    const float* bih1      = (const float*)d_in[10];
    const float* bhh1      = (const float*)d_in[11];
    const float* W1        = (const float*)d_in[12];
    const float* b1        = (const float*)d_in[13];
    const float* W2        = (const float*)d_in[14];
    const float* b2        = (const float*)d_in[15];
    float* out = (float*)d_out;

    const size_t NT = (size_t)B_ * T_;               // 131072
    const size_t need = NT * G3_ * 4 + NT * H_ * 4;  // 256 MiB
    if (ws_size < need) {
        hipMemsetAsync(d_out, 0x7F, (size_t)out_size * 4, stream);
        return;
    }
    float* gi = (float*)d_ws;
    float* hb = gi + NT * G3_;                       // h1, then reused as h2

    const int gblocks = (int)(NT / 128);             // 1024
    gemm_gi_mfma<<<gblocks, 512, 0, stream>>>(x, Wih0, bih0, gi);
    gru_seq<<<B_, 512, 0, stream>>>(gi, Whh0, bhh0, hb);
    gemm_gi_mfma<<<gblocks, 512, 0, stream>>>(hb, Wih1, bih1, gi);
    gru_seq<<<B_, 512, 0, stream>>>(gi, Whh1, bhh1, hb);
    head_k<<<(int)(NT / 4), 256, 0, stream>>>(hb, x, regime, W1, b1, W2, b2,
                                              lag_scale, lag_bias, out);
}